// Round 14
// baseline (243.598 us; speedup 1.0000x reference)
//
#include <hip/hip_runtime.h>
#include <hip/hip_bf16.h>
#include <math.h>

// Dims fixed by setup_inputs(): B=16, S=2048, D=1024, H=16, hd=64, P=8,
// cls=1, pma=8, recent=64, T=73.

#define Bn 16
#define Sn 2048
#define Dn 1024
#define Hn 16
#define Pn 8
#define Tn 73
#define RECn 64
#define UPITCH 520   // U-staging LDS pitch in shorts (breaks bank-0 collapse)

typedef __attribute__((ext_vector_type(8))) short short8;
typedef __attribute__((ext_vector_type(4))) float f32x4;

__device__ __forceinline__ short f2bf(float x) {
    union { __hip_bfloat16 h; short s; } u;
    u.h = __float2bfloat16(x);   // native v_cvt, RNE
    return u.s;
}
__device__ __forceinline__ float bf2f(short s) {
    return __uint_as_float(((unsigned)(unsigned short)s) << 16);
}

// valid_mask accessor: dtype decided at runtime by flag (1 = uint8, 0 = int32).
__device__ __forceinline__ bool mask_at(const void* raw, int f, size_t idx) {
    return f ? (((const unsigned char*)raw)[idx] != 0)
             : (((const int*)raw)[idx] != 0);
}

// ---------------------------------------------------------------- setup1: mask-dtype detect (block 2048) + q = queries@Wq^T+bq (blocks 0..2047)
__global__ __launch_bounds__(256) void setup1_kernel(const float* __restrict__ queries,
                                                     const float* __restrict__ in_w,
                                                     const float* __restrict__ in_b,
                                                     const unsigned char* __restrict__ raw,
                                                     float* __restrict__ q,
                                                     int* __restrict__ flag) {
    if (blockIdx.x == 2048) {
        __shared__ int any;
        if (threadIdx.x == 0) any = 0;
        __syncthreads();
        const uint4* r4 = (const uint4*)raw;
        int local = 0;
        for (int i = threadIdx.x; i < (Bn * Sn) / 16; i += blockDim.x) {
            uint4 w = r4[i];
            if ((w.x & 0xFFFFFF00u) | (w.y & 0xFFFFFF00u) |
                (w.z & 0xFFFFFF00u) | (w.w & 0xFFFFFF00u)) local = 1;
        }
        if (local) any = 1;                   // benign race
        __syncthreads();
        if (threadIdx.x == 0) *flag = any;
        return;
    }
    int wid = (blockIdx.x * blockDim.x + threadIdx.x) >> 6;
    int lane = threadIdx.x & 63;
    if (wid >= Pn * Dn) return;
    int p = wid >> 10, j = wid & 1023;
    float acc = 0.0f;
    for (int c = lane; c < Dn; c += 64)
        acc += queries[p * Dn + c] * in_w[(size_t)j * Dn + c];
#pragma unroll
    for (int off = 32; off > 0; off >>= 1) acc += __shfl_down(acc, off);
    if (lane == 0) q[wid] = acc + in_b[j];
}

// ---------------------------------------------------------------- setup2: Btile (blocks 0..63) + prep scan (blocks 64..79)
// Btile is MFMA-fragment-linear: the short8 for lane (q,l15) of fragment
// (kc,nt) lives at ((kc*8+nt)*64 + q*16 + l15)*8. A wave's B-frag load is
// then 64 lanes x 16B CONTIGUOUS (1 request/instr) -- no TA shatter.
__global__ __launch_bounds__(256) void setup2_kernel(const float* __restrict__ q,
                                                     const float* __restrict__ in_w,
                                                     const float* __restrict__ in_b,
                                                     const void* __restrict__ raw,
                                                     const int* __restrict__ flag,
                                                     short* __restrict__ Btile,
                                                     float* __restrict__ c0,
                                                     int* __restrict__ totals,
                                                     int* __restrict__ rsrc,
                                                     float* __restrict__ maskf) {
    __shared__ float qs[8][64];
    __shared__ int lc[256];
    if (blockIdx.x < 64) {                    // ---- Btile + c0
        int h = blockIdx.x >> 2, cblk = blockIdx.x & 3;
        int c = cblk * 256 + threadIdx.x;
        for (int i = threadIdx.x; i < 512; i += 256) {
            int p = i >> 6, d = i & 63;
            qs[p][d] = q[p * Dn + h * 64 + d];
        }
        __syncthreads();
        float acc[8] = {};
#pragma unroll 8
        for (int d = 0; d < 64; d++) {
            float w = in_w[(size_t)(Dn + h * 64 + d) * Dn + c];
#pragma unroll
            for (int p = 0; p < 8; p++) acc[p] = fmaf(qs[p][d], w, acc[p]);
        }
        int kc = c >> 5, kq = (c >> 3) & 3, e = c & 7;
#pragma unroll
        for (int p = 0; p < 8; p++) {
            int hp = h * 8 + p;
            size_t slot = (size_t)(kc * 8 + (hp >> 4)) * 64 + kq * 16 + (hp & 15);
            Btile[slot * 8 + e] = f2bf(acc[p] * 0.125f);
        }
        if (cblk == 0 && threadIdx.x < 8) {
            int p = threadIdx.x;
            float a = 0.0f;
            for (int d = 0; d < 64; d++) a += qs[p][d] * in_b[Dn + h * 64 + d];
            c0[h * 8 + p] = a * 0.125f;
        }
        return;
    }
    // ---- prep: per-batch scan, recent gather indices, summary mask
    int b = blockIdx.x - 64, t = threadIdx.x;
    int f = *flag;
    const int SP = Sn - 1;                    // 2047
    if (t < RECn) rsrc[b * RECn + t] = -1;
    int base = t * 8;
    unsigned char m[8];
    int cnt = 0;
#pragma unroll
    for (int i = 0; i < 8; i++) {
        int idx = base + i;
        m[i] = (idx < SP) ? (mask_at(raw, f, (size_t)b * Sn + 1 + idx) ? 1 : 0) : 0;
        cnt += m[i];
    }
    lc[t] = cnt;
    __syncthreads();
    for (int off = 1; off < 256; off <<= 1) {
        int add = (t >= off) ? lc[t - off] : 0;
        __syncthreads();
        lc[t] += add;
        __syncthreads();
    }
    int total = lc[255];
    int run = lc[t] - cnt;                    // exclusive prefix
#pragma unroll
    for (int i = 0; i < 8; i++) {
        if (m[i]) {
            run++;
            int rank = total - run;
            if (rank < RECn) rsrc[b * RECn + (RECn - 1 - rank)] = base + i + 1;
        }
    }
    if (t == 0) totals[b] = total;
    if (t < Tn) {
        float mv;
        if (t == 0) mv = mask_at(raw, f, (size_t)b * Sn) ? 1.0f : 0.0f;
        else if (t < 1 + Pn) mv = 1.0f;
        else mv = ((t - 9) >= RECn - total) ? 1.0f : 0.0f;
        maskf[b * Tn + t] = mv;
    }
}

// ---------------------------------------------------------------- scores[b,hp,s] = hidden[b,s,:]@A[hp,:] + c0 (MFMA bf16), masked
// v6: BARRIER-FREE, LDS-FREE. 512 blocks x 256 thr (4 waves; 2 blocks/CU,
// 8 waves/CU). Wave owns 16 s-rows x all 128 hp: 8 independent MFMA chains.
// B-frags register-loaded from the frag-linear Btile (L2-resident, 1 KB
// contiguous per instr); A (hidden) streamed f32 with in-reg cvt. 1-step
// register prefetch on both; no vmcnt(0) drain anywhere in the loop.
__global__ __launch_bounds__(256) void scores_mfma(const float* __restrict__ hidden,
                                                   const short* __restrict__ Btile,
                                                   const float* __restrict__ c0,
                                                   const void* __restrict__ raw,
                                                   const int* __restrict__ flag,
                                                   float* __restrict__ scores) {
    int tid = threadIdx.x, wave = tid >> 6, lane = tid & 63;
    int l15 = lane & 15, q = lane >> 4;
    int m0 = blockIdx.x * 64 + wave * 16;
    int b = m0 >> 11, s_base = m0 & 2047;

    const float* aptr = hidden + (size_t)(m0 + l15) * Dn + q * 8;
    const short* bbase = Btile + (size_t)lane * 8;

    f32x4 acc[8] = {};
    short8 bcur[8], bnxt[8];
    f32x4 a0c = *(const f32x4*)(aptr);
    f32x4 a1c = *(const f32x4*)(aptr + 4);
    f32x4 a0n, a1n;
#pragma unroll
    for (int nt = 0; nt < 8; nt++)
        bcur[nt] = *(const short8*)(bbase + (size_t)nt * 512);

    for (int kc = 0; kc < 32; kc++) {
        if (kc + 1 < 32) {
#pragma unroll
            for (int nt = 0; nt < 8; nt++)
                bnxt[nt] = *(const short8*)(bbase + (size_t)((kc + 1) * 8 + nt) * 512);
            a0n = *(const f32x4*)(aptr + (kc + 1) * 32);
            a1n = *(const f32x4*)(aptr + (kc + 1) * 32 + 4);
        }
        short8 av;
#pragma unroll
        for (int i = 0; i < 4; i++) { av[i] = f2bf(a0c[i]); av[i + 4] = f2bf(a1c[i]); }
#pragma unroll
        for (int nt = 0; nt < 8; nt++)
            acc[nt] = __builtin_amdgcn_mfma_f32_16x16x32_bf16(av, bcur[nt], acc[nt], 0, 0, 0);
#pragma unroll
        for (int nt = 0; nt < 8; nt++) bcur[nt] = bnxt[nt];
        a0c = a0n; a1c = a1n;
    }

    // epilogue: C/D layout col=lane&15 (hp), row=q*4+reg (s); +c0, mask
    int fl = *flag;
    int srow = s_base + q * 4;
    size_t vbase = (size_t)b * Sn + srow;
    bool ok0 = mask_at(raw, fl, vbase), ok1 = mask_at(raw, fl, vbase + 1);
    bool ok2 = mask_at(raw, fl, vbase + 2), ok3 = mask_at(raw, fl, vbase + 3);
#pragma unroll
    for (int nt = 0; nt < 8; nt++) {
        int hp = nt * 16 + l15;
        float cc = c0[hp];
        f32x4 st;
        st[0] = ok0 ? acc[nt][0] + cc : -1.0e9f;
        st[1] = ok1 ? acc[nt][1] + cc : -1.0e9f;
        st[2] = ok2 ? acc[nt][2] + cc : -1.0e9f;
        st[3] = ok3 ? acc[nt][3] + cc : -1.0e9f;
        *(f32x4*)(scores + (size_t)(b * 128 + hp) * Sn + srow) = st;
    }
}

// ---------------------------------------------------------------- softmax over s; writes bf16 attn
__global__ __launch_bounds__(256) void softmax_kernel(const float* __restrict__ scores,
                                                      short* __restrict__ attn_bf) {
    const float* row = scores + (size_t)blockIdx.x * Sn;
    short* orow = attn_bf + (size_t)blockIdx.x * Sn;
    int t = threadIdx.x;
    __shared__ float red[256];
    f32x4 v0 = *(const f32x4*)(row + t * 8);
    f32x4 v1 = *(const f32x4*)(row + t * 8 + 4);
    float mx = -1.0e30f;
#pragma unroll
    for (int i = 0; i < 4; i++) { mx = fmaxf(mx, v0[i]); mx = fmaxf(mx, v1[i]); }
    red[t] = mx;
    __syncthreads();
    for (int off = 128; off > 0; off >>= 1) {
        if (t < off) red[t] = fmaxf(red[t], red[t + off]);
        __syncthreads();
    }
    mx = red[0];
    __syncthreads();
    float e[8];
    float sum = 0.0f;
#pragma unroll
    for (int i = 0; i < 4; i++) {
        e[i] = expf(v0[i] - mx); sum += e[i];
        e[i + 4] = expf(v1[i] - mx); sum += e[i + 4];
    }
    red[t] = sum;
    __syncthreads();
    for (int off = 128; off > 0; off >>= 1) {
        if (t < off) red[t] += red[t + off];
        __syncthreads();
    }
    float inv = 1.0f / red[0];
    short8 o;
#pragma unroll
    for (int i = 0; i < 8; i++) o[i] = f2bf(e[i] * inv);
    *(short8*)(orow + t * 8) = o;
}

// ---------------------------------------------------------------- U partials (bf16): Up[b,hp,c] = sum_{s in z-chunk} attn*hidden
// grid (16 c-tiles of 64, 16 b, 4 z) x 512 threads. Coalesced transpose
// staging (4x256B/instr), LDS pitch 520; attn streams 4-deep; barrier-free.
__global__ __launch_bounds__(512) void U_mfma(const short* __restrict__ attn_bf,
                                              const float* __restrict__ hidden,
                                              short* __restrict__ Up0,
                                              short* __restrict__ Up1,
                                              short* __restrict__ Up2,
                                              short* __restrict__ Up3) {
    __shared__ short Hs[64 * UPITCH];         // 64 c x 512 s (pitch 520), swizzled
    int n0 = blockIdx.x * 64, b = blockIdx.y, z = blockIdx.z;
    int zbase = z * 512;
    short* Up = (z == 0) ? Up0 : (z == 1) ? Up1 : (z == 2) ? Up2 : Up3;
    int tid = threadIdx.x, wave = tid >> 6, lane = tid & 63;
    int l15 = lane & 15, q = lane >> 4;

    {   // coalesced transpose staging
        int slot = tid & 15, rgrp = tid >> 4;
        const float* srcb = hidden + ((size_t)b * Sn + zbase) * Dn + n0 + slot * 4;
#pragma unroll
        for (int p = 0; p < 16; p++) {
            int row = p * 32 + rgrp;
            f32x4 v = *(const f32x4*)(srcb + (size_t)row * Dn);
#pragma unroll
            for (int i = 0; i < 4; i++) {
                int c = slot * 4 + i;
                Hs[c * UPITCH + (row ^ ((c & 7) << 3))] = f2bf(v[i]);
            }
        }
    }
    __syncthreads();                          // the only barrier

    const short* ap = attn_bf + ((size_t)b * 128 + wave * 16 + l15) * Sn + zbase + q * 8;
    f32x4 acc[4] = {};
    short8 pa4[4];
#pragma unroll
    for (int d = 0; d < 4; d++) pa4[d] = *(const short8*)(ap + d * 32);
#pragma unroll
    for (int ic = 0; ic < 16; ic++) {
        short8 av = pa4[ic & 3];
        if (ic + 4 < 16) pa4[ic & 3] = *(const short8*)(ap + (ic + 4) * 32);
#pragma unroll
        for (int nf = 0; nf < 4; nf++) {
            int c = nf * 16 + l15;
            int ks = (ic * 32 + q * 8) ^ ((c & 7) << 3);
            short8 bv = *(const short8*)(&Hs[c * UPITCH + ks]);
            acc[nf] = __builtin_amdgcn_mfma_f32_16x16x32_bf16(av, bv, acc[nf], 0, 0, 0);
        }
    }
    int hp = wave * 16 + q * 4;
#pragma unroll
    for (int nf = 0; nf < 4; nf++) {
        int c = n0 + nf * 16 + l15;
        short* up = Up + (size_t)(b * 128 + hp) * Dn + c;
#pragma unroll
        for (int r = 0; r < 4; r++) up[(size_t)r * Dn] = f2bf(acc[nf][r]);
    }
}

// ---------------------------------------------------------------- ctx[bp, h*64+d] = (sum Up)[b,h*8+p,:] . Wv[h*64+d,:] + bv  (MFMA)
__global__ __launch_bounds__(64) void ctx_mfma(const short* __restrict__ Up0,
                                               const short* __restrict__ Up1,
                                               const short* __restrict__ Up2,
                                               const short* __restrict__ Up3,
                                               const float* __restrict__ in_w,
                                               const float* __restrict__ in_b,
                                               float* __restrict__ ctx) {
    int bh = blockIdx.x, b = bh >> 4, h = bh & 15;
    int lane = threadIdx.x & 63, l15 = lane & 15, koff = (lane >> 4) * 8;
    int p = l15 & 7;
    size_t uoff = ((size_t)b * 128 + h * 8 + p) * Dn + koff;
    const float* wv = in_w + (size_t)(2 * Dn + h * 64 + l15) * Dn + koff;
    f32x4 acc[4] = {};
    for (int k0 = 0; k0 < Dn; k0 += 32) {
        short8 s0 = *(const short8*)(Up0 + uoff + k0);
        short8 s1 = *(const short8*)(Up1 + uoff + k0);
        short8 s2 = *(const short8*)(Up2 + uoff + k0);
        short8 s3 = *(const short8*)(Up3 + uoff + k0);
        short8 av;
#pragma unroll
        for (int i = 0; i < 8; i++)
            av[i] = f2bf((bf2f(s0[i]) + bf2f(s1[i])) + (bf2f(s2[i]) + bf2f(s3[i])));
#pragma unroll
        for (int nt = 0; nt < 4; nt++) {
            f32x4 w0 = *(const f32x4*)(wv + (size_t)nt * 16 * Dn + k0);
            f32x4 w1 = *(const f32x4*)(wv + (size_t)nt * 16 * Dn + k0 + 4);
            short8 bv;
#pragma unroll
            for (int i = 0; i < 4; i++) { bv[i] = f2bf(w0[i]); bv[i + 4] = f2bf(w1[i]); }
            acc[nt] = __builtin_amdgcn_mfma_f32_16x16x32_bf16(av, bv, acc[nt], 0, 0, 0);
        }
    }
    if (lane < 32) {                          // rows 0-7 valid (p)
        int prow = (lane >> 4) * 4;
#pragma unroll
        for (int nt = 0; nt < 4; nt++) {
            int d = h * 64 + nt * 16 + l15;
            float bias = in_b[2 * Dn + d];
#pragma unroll
            for (int r = 0; r < 4; r++)
                ctx[(size_t)(b * 8 + prow + r) * Dn + d] = acc[nt][r] + bias;
        }
    }
}

// ---------------------------------------------------------------- pooled = ctx @ out_w^T + out_b (MFMA, f32 operands cvt in-reg)
__global__ __launch_bounds__(256) void pooled_mfma(const float* __restrict__ A,
                                                   const float* __restrict__ B,
                                                   const float* __restrict__ bias,
                                                   float* __restrict__ C, int M) {
    int wave = threadIdx.x >> 6, lane = threadIdx.x & 63;
    int l15 = lane & 15, koff = (lane >> 4) * 8;
    int m0 = blockIdx.x * 64 + (wave >> 1) * 32;
    int n0 = blockIdx.y * 64 + (wave & 1) * 32;
    f32x4 acc[2][2] = {};
    int ra0 = min(m0 + l15, M - 1);
    int ra1 = min(m0 + 16 + l15, M - 1);
    const float* a0p = A + (size_t)ra0 * Dn + koff;
    const float* a1p = A + (size_t)ra1 * Dn + koff;
    const float* b0p = B + (size_t)(n0 + l15) * Dn + koff;
    const float* b1p = B + (size_t)(n0 + 16 + l15) * Dn + koff;
    for (int k0 = 0; k0 < Dn; k0 += 32) {
        short8 av0, av1, bv0, bv1;
        f32x4 x, y;
        x = *(const f32x4*)(a0p + k0); y = *(const f32x4*)(a0p + k0 + 4);
#pragma unroll
        for (int i = 0; i < 4; i++) { av0[i] = f2bf(x[i]); av0[i + 4] = f2bf(y[i]); }
        x = *(const f32x4*)(a1p + k0); y = *(const f32x4*)(a1p + k0 + 4);
#pragma unroll
        for (int i = 0; i < 4; i++) { av1[i] = f2bf(x[i]); av1[i + 4] = f2bf(y[i]); }
        x = *(const f32x4*)(b0p + k0); y = *(const f32x4*)(b0p + k0 + 4);
#pragma unroll
        for (int i = 0; i < 4; i++) { bv0[i] = f2bf(x[i]); bv0[i + 4] = f2bf(y[i]); }
        x = *(const f32x4*)(b1p + k0); y = *(const f32x4*)(b1p + k0 + 4);
#pragma unroll
        for (int i = 0; i < 4; i++) { bv1[i] = f2bf(x[i]); bv1[i + 4] = f2bf(y[i]); }
        acc[0][0] = __builtin_amdgcn_mfma_f32_16x16x32_bf16(av0, bv0, acc[0][0], 0, 0, 0);
        acc[0][1] = __builtin_amdgcn_mfma_f32_16x16x32_bf16(av0, bv1, acc[0][1], 0, 0, 0);
        acc[1][0] = __builtin_amdgcn_mfma_f32_16x16x32_bf16(av1, bv0, acc[1][0], 0, 0, 0);
        acc[1][1] = __builtin_amdgcn_mfma_f32_16x16x32_bf16(av1, bv1, acc[1][1], 0, 0, 0);
    }
#pragma unroll
    for (int mf = 0; mf < 2; mf++) {
        int row0 = m0 + mf * 16 + (lane >> 4) * 4;
#pragma unroll
        for (int nf = 0; nf < 2; nf++) {
            int col = n0 + nf * 16 + l15;
            float bval = bias[col];
#pragma unroll
            for (int r = 0; r < 4; r++) {
                int row = row0 + r;
                if (row < M) C[(size_t)row * Dn + col] = acc[mf][nf][r] + bval;
            }
        }
    }
}

// ---------------------------------------------------------------- merged W-GEMMs: z=0: c1=lnv@Wv^T+bv, z=1: c2=lng@Wg^T+bg
__global__ __launch_bounds__(256) void wgemm_mfma(const short* __restrict__ lnv,
                                                  const short* __restrict__ lng,
                                                  const float* __restrict__ Wv,
                                                  const float* __restrict__ Wg,
                                                  const float* __restrict__ bv_,
                                                  const float* __restrict__ bg_,
                                                  float* __restrict__ c1,
                                                  float* __restrict__ c2, int M) {
    int z = blockIdx.z;
    const short* Abf = z ? lng : lnv;
    const float* Bw = z ? Wg : Wv;
    const float* bias = z ? bg_ : bv_;
    float* C = z ? c2 : c1;
    int wave = threadIdx.x >> 6, lane = threadIdx.x & 63;
    int l15 = lane & 15, koff = (lane >> 4) * 8;
    int m0 = blockIdx.x * 64 + (wave >> 1) * 32;
    int n0 = blockIdx.y * 64 + (wave & 1) * 32;
    f32x4 acc[2][2] = {};
    int ra0 = min(m0 + l15, M - 1);
    int ra1 = min(m0 + 16 + l15, M - 1);
    const short* a0p = Abf + (size_t)ra0 * Dn + koff;
    const short* a1p = Abf + (size_t)ra1 * Dn + koff;
    const float* b0p = Bw + (size_t)(n0 + l15) * Dn + koff;
    const float* b1p = Bw + (size_t)(n0 + 16 + l15) * Dn + koff;
    for (int k0 = 0; k0 < Dn; k0 += 32) {
        short8 av0 = *(const short8*)(a0p + k0);
        short8 av1 = *(const short8*)(a1p + k0);
        short8 bv0, bv1;
        f32x4 x, y;
        x = *(const f32x4*)(b0p + k0); y = *(const f32x4*)(b0p + k0 + 4);
#pragma unroll
        for (int i = 0; i < 4; i++) { bv0[i] = f2bf(x[i]); bv0[i + 4] = f2bf(y[i]); }
        x = *(const f32x4*)(b1p + k0); y = *(const f32x4*)(b1p + k0 + 4);
#pragma unroll
        for (int i = 0; i < 4; i++) { bv1[i] = f2bf(x[i]); bv1[i + 4] = f2bf(y[i]); }
        acc[0][0] = __builtin_amdgcn_mfma_f32_16x16x32_bf16(av0, bv0, acc[0][0], 0, 0, 0);
        acc[0][1] = __builtin_amdgcn_mfma_f32_16x16x32_bf16(av0, bv1, acc[0][1], 0, 0, 0);
        acc[1][0] = __builtin_amdgcn_mfma_f32_16x16x32_bf16(av1, bv0, acc[1][0], 0, 0, 0);
        acc[1][1] = __builtin_amdgcn_mfma_f32_16x16x32_bf16(av1, bv1, acc[1][1], 0, 0, 0);
    }
#pragma unroll
    for (int mf = 0; mf < 2; mf++) {
        int row0 = m0 + mf * 16 + (lane >> 4) * 4;
#pragma unroll
        for (int nf = 0; nf < 2; nf++) {
            int col = n0 + nf * 16 + l15;
            float bval = bias[col];
#pragma unroll
            for (int r = 0; r < 4; r++) {
                int row = row0 + r;
                if (row < M) C[(size_t)row * Dn + col] = acc[mf][nf][r] + bval;
            }
        }
    }
}

// ---------------------------------------------------------------- block sum helper
__device__ __forceinline__ float block_sum(float v, float* red) {
    int tid = threadIdx.x;
    red[tid] = v;
    __syncthreads();
    for (int off = 128; off > 0; off >>= 1) {
        if (tid < off) red[tid] += red[tid + off];
        __syncthreads();
    }
    float r = red[0];
    __syncthreads();
    return r;
}

// ---------------------------------------------------------------- build summary row + LN_pma + LN_v / LN_g (bf16 out)
__global__ void summary_ln_kernel(const float* __restrict__ hidden,
                                  const float* __restrict__ queries,
                                  const float* __restrict__ pooled,
                                  const int* __restrict__ rsrc,
                                  const float* __restrict__ gpma, const float* __restrict__ bpma,
                                  const float* __restrict__ gv, const float* __restrict__ bv,
                                  const float* __restrict__ gg, const float* __restrict__ bg,
                                  short* __restrict__ lnv, short* __restrict__ lng) {
    __shared__ float red[256];
    int b = blockIdx.x, t = blockIdx.y, tid = threadIdx.x;
    float x[4];
    if (t == 0) {
#pragma unroll
        for (int i = 0; i < 4; i++)
            x[i] = hidden[(size_t)b * Sn * Dn + tid + i * 256];
    } else if (t < 1 + Pn) {
        int p = t - 1;
#pragma unroll
        for (int i = 0; i < 4; i++) {
            int c = tid + i * 256;
            x[i] = queries[p * Dn + c] + pooled[((size_t)b * Pn + p) * Dn + c];
        }
    } else {
        int src = rsrc[b * RECn + (t - 9)];
        if (src >= 0) {
#pragma unroll
            for (int i = 0; i < 4; i++)
                x[i] = hidden[((size_t)b * Sn + src) * Dn + tid + i * 256];
        } else {
#pragma unroll
            for (int i = 0; i < 4; i++) x[i] = 0.0f;
        }
    }
    if (t >= 1 && t < 1 + Pn) {
        float mu = block_sum(x[0] + x[1] + x[2] + x[3], red) * (1.0f / Dn);
        float d2 = 0.0f;
#pragma unroll
        for (int i = 0; i < 4; i++) { float d = x[i] - mu; d2 += d * d; }
        float inv = rsqrtf(block_sum(d2, red) * (1.0f / Dn) + 1e-5f);
#pragma unroll
        for (int i = 0; i < 4; i++) {
            int c = tid + i * 256;
            x[i] = (x[i] - mu) * inv * gpma[c] + bpma[c];
        }
    }
    float mu = block_sum(x[0] + x[1] + x[2] + x[3], red) * (1.0f / Dn);
    float d2 = 0.0f;
#pragma unroll
    for (int i = 0; i < 4; i++) { float d = x[i] - mu; d2 += d * d; }
    float inv = rsqrtf(block_sum(d2, red) * (1.0f / Dn) + 1e-5f);
    size_t row = (size_t)(b * Tn + t) * Dn;
#pragma unroll
    for (int i = 0; i < 4; i++) {
        int c = tid + i * 256;
        float xh = (x[i] - mu) * inv;
        lnv[row + c] = f2bf(xh * gv[c] + bv[c]);
        lng[row + c] = f2bf(xh * gg[c] + bg[c]);
    }
}

// ---------------------------------------------------------------- gated = sigmoid(c2) * silu(c1) * mask
__global__ void gated_kernel(const float* __restrict__ c1, const float* __restrict__ c2,
                             const float* __restrict__ maskf, float* __restrict__ out) {
    int gi = blockIdx.x * blockDim.x + threadIdx.x;
    int row = gi >> 10;
    float m = maskf[row];
    float a = c1[gi], g = c2[gi];
    float sv = a / (1.0f + expf(-a));
    float sg = 1.0f / (1.0f + expf(-g));
    out[gi] = sg * sv * m;
}

// ================================================================ launch
extern "C" void kernel_launch(void* const* d_in, const int* in_sizes, int n_in,
                              void* d_out, int out_size, void* d_ws, size_t ws_size,
                              hipStream_t stream) {
    const float* hidden = (const float*)d_in[0];
    const void* valid_raw = d_in[1];
    const float* queries = (const float*)d_in[2];
    const float* in_w = (const float*)d_in[3];
    const float* in_b = (const float*)d_in[4];
    const float* out_w = (const float*)d_in[5];
    const float* out_b = (const float*)d_in[6];
    const float* ln_pma_g = (const float*)d_in[7];
    const float* ln_pma_b = (const float*)d_in[8];
    const float* ln_v_g = (const float*)d_in[9];
    const float* ln_v_b = (const float*)d_in[10];
    const float* W_v = (const float*)d_in[11];
    const float* b_v = (const float*)d_in[12];
    const float* ln_g_g = (const float*)d_in[13];
    const float* ln_g_b = (const float*)d_in[14];
    const float* W_g = (const float*)d_in[15];
    const float* b_g = (const float*)d_in[16];

    float* ws = (float*)d_ws;
    float* out = (float*)d_out;

    // workspace layout (float offsets):
    float* SC      = ws;                         // scores f32: 4,194,304 f (dead after softmax)
    short* attn_bf = (short*)(ws + 4194304);     // 4,194,304 shorts = 2,097,152 f
    short* Up0     = (short*)ws;                 // bf16 partials overlay dead SC:
    short* Up1     = (short*)(ws + 1048576);     //   each 2,097,152 shorts = 1,048,576 f
    short* Up2     = (short*)(ws + 2097152);
    short* Up3     = (short*)(ws + 3145728);     // ends 4,194,304 (SC region exactly)
    float* qbuf    = ws + 10485760;              // 8,192
    short* Btile   = (short*)(ws + 10493952);    // 131,072 shorts = 65,536 f
    float* c0      = ws + 10559488;              // 256
    float* ctx     = ws + 10559744;              // 131,072
    float* pooled  = ws + 10690816;              // 131,072
    int*   ivals   = (int*)(ws + 11870464);
    int* totals = ivals;                         // 16
    int* rsrc = ivals + 16;                      // 1024
    int* flag = ivals + 16 + 1024;               // 16
    // post-ctx overlays (Up0..3 dead after ctx):
    short* lnv_bf = (short*)ws;                  // 1168*1024 shorts
    short* lng_bf = (short*)(ws + 622592);
    float* c1 = ws + 1245184;
    float* c2 = ws + 2441216;                    // ends 3,637,248 OK
    float* maskf = out + (size_t)Bn * Tn * Dn;

    const int M2 = Bn * Tn; // 1168

    setup1_kernel<<<2049, 256, 0, stream>>>(queries, in_w, in_b,
                                            (const unsigned char*)valid_raw, qbuf, flag);
    setup2_kernel<<<80, 256, 0, stream>>>(qbuf, in_w, in_b, valid_raw, flag,
                                          Btile, c0, totals, rsrc, maskf);
    scores_mfma<<<(Bn * Sn) / 64, 256, 0, stream>>>(hidden, Btile, c0, valid_raw, flag, SC);
    softmax_kernel<<<Bn * 128, 256, 0, stream>>>(SC, attn_bf);
    U_mfma<<<dim3(16, Bn, 4), 512, 0, stream>>>(attn_bf, hidden, Up0, Up1, Up2, Up3);
    ctx_mfma<<<Bn * Hn, 64, 0, stream>>>(Up0, Up1, Up2, Up3, in_w, in_b, ctx);
    pooled_mfma<<<dim3(2, 16), 256, 0, stream>>>(ctx, out_w, out_b, pooled, Bn * Pn);
    summary_ln_kernel<<<dim3(Bn, Tn), 256, 0, stream>>>(hidden, queries, pooled, rsrc,
                                                        ln_pma_g, ln_pma_b, ln_v_g, ln_v_b,
                                                        ln_g_g, ln_g_b, lnv_bf, lng_bf);
    wgemm_mfma<<<dim3((M2 + 63) / 64, 16, 2), 256, 0, stream>>>(lnv_bf, lng_bf, W_v, W_g,
                                                                b_v, b_g, c1, c2, M2);
    gated_kernel<<<(Bn * Tn * Dn) / 256, 256, 0, stream>>>(c1, c2, maskf, out);
}

// Round 15
// 232.325 us; speedup vs baseline: 1.0485x; 1.0485x over previous
//
#include <hip/hip_runtime.h>
#include <hip/hip_bf16.h>
#include <math.h>

// Dims fixed by setup_inputs(): B=16, S=2048, D=1024, H=16, hd=64, P=8,
// cls=1, pma=8, recent=64, T=73.

#define Bn 16
#define Sn 2048
#define Dn 1024
#define Hn 16
#define Pn 8
#define Tn 73
#define RECn 64
#define UPITCH 520   // U-staging LDS pitch in shorts (breaks bank-0 collapse)

typedef __attribute__((ext_vector_type(8))) short short8;
typedef __attribute__((ext_vector_type(4))) float f32x4;

__device__ __forceinline__ short f2bf(float x) {
    union { __hip_bfloat16 h; short s; } u;
    u.h = __float2bfloat16(x);   // native v_cvt, RNE
    return u.s;
}
__device__ __forceinline__ float bf2f(short s) {
    return __uint_as_float(((unsigned)(unsigned short)s) << 16);
}

// valid_mask accessor: dtype decided at runtime by flag (1 = uint8, 0 = int32).
__device__ __forceinline__ bool mask_at(const void* raw, int f, size_t idx) {
    return f ? (((const unsigned char*)raw)[idx] != 0)
             : (((const int*)raw)[idx] != 0);
}

// async global->LDS DMA, 16B per lane. LDS dest = wave-uniform base + lane*16.
__device__ __forceinline__ void gload_lds16(const void* g, void* l) {
    __builtin_amdgcn_global_load_lds((const __attribute__((address_space(1))) void*)g,
                                     (__attribute__((address_space(3))) void*)l, 16, 0, 0);
}

// ---------------------------------------------------------------- setup1: mask-dtype detect (block 2048) + q = queries@Wq^T+bq (blocks 0..2047)
__global__ __launch_bounds__(256) void setup1_kernel(const float* __restrict__ queries,
                                                     const float* __restrict__ in_w,
                                                     const float* __restrict__ in_b,
                                                     const unsigned char* __restrict__ raw,
                                                     float* __restrict__ q,
                                                     int* __restrict__ flag) {
    if (blockIdx.x == 2048) {
        __shared__ int any;
        if (threadIdx.x == 0) any = 0;
        __syncthreads();
        const uint4* r4 = (const uint4*)raw;
        int local = 0;
        for (int i = threadIdx.x; i < (Bn * Sn) / 16; i += blockDim.x) {
            uint4 w = r4[i];
            if ((w.x & 0xFFFFFF00u) | (w.y & 0xFFFFFF00u) |
                (w.z & 0xFFFFFF00u) | (w.w & 0xFFFFFF00u)) local = 1;
        }
        if (local) any = 1;                   // benign race
        __syncthreads();
        if (threadIdx.x == 0) *flag = any;
        return;
    }
    int wid = (blockIdx.x * blockDim.x + threadIdx.x) >> 6;
    int lane = threadIdx.x & 63;
    if (wid >= Pn * Dn) return;
    int p = wid >> 10, j = wid & 1023;
    float acc = 0.0f;
    for (int c = lane; c < Dn; c += 64)
        acc += queries[p * Dn + c] * in_w[(size_t)j * Dn + c];
#pragma unroll
    for (int off = 32; off > 0; off >>= 1) acc += __shfl_down(acc, off);
    if (lane == 0) q[wid] = acc + in_b[j];
}

// ---------------------------------------------------------------- setup2: Atile (blocks 0..63) + prep scan (blocks 64..79)
// Atile layout = the scores kernel's per-chunk LDS image:
//   Atile[kc][slot][e], kc=c>>5, kq=(c>>3)&3, e=c&7, slot=hp*4+(kq^((hp>>1)&3))
// so the B-stage DMA is a LINEAR 8KB copy per K-chunk (TA-coalesced).
__global__ __launch_bounds__(256) void setup2_kernel(const float* __restrict__ q,
                                                     const float* __restrict__ in_w,
                                                     const float* __restrict__ in_b,
                                                     const void* __restrict__ raw,
                                                     const int* __restrict__ flag,
                                                     short* __restrict__ Atile,
                                                     float* __restrict__ c0,
                                                     int* __restrict__ totals,
                                                     int* __restrict__ rsrc,
                                                     float* __restrict__ maskf) {
    __shared__ float qs[8][64];
    __shared__ int lc[256];
    if (blockIdx.x < 64) {                    // ---- Atile + c0
        int h = blockIdx.x >> 2, cblk = blockIdx.x & 3;
        int c = cblk * 256 + threadIdx.x;
        for (int i = threadIdx.x; i < 512; i += 256) {
            int p = i >> 6, d = i & 63;
            qs[p][d] = q[p * Dn + h * 64 + d];
        }
        __syncthreads();
        float acc[8] = {};
#pragma unroll 8
        for (int d = 0; d < 64; d++) {
            float w = in_w[(size_t)(Dn + h * 64 + d) * Dn + c];
#pragma unroll
            for (int p = 0; p < 8; p++) acc[p] = fmaf(qs[p][d], w, acc[p]);
        }
        int kc = c >> 5, kq = (c >> 3) & 3, e = c & 7;
#pragma unroll
        for (int p = 0; p < 8; p++) {
            int hp = h * 8 + p;
            int slot = hp * 4 + (kq ^ ((hp >> 1) & 3));
            Atile[(size_t)kc * 4096 + slot * 8 + e] = f2bf(acc[p] * 0.125f);
        }
        if (cblk == 0 && threadIdx.x < 8) {
            int p = threadIdx.x;
            float a = 0.0f;
            for (int d = 0; d < 64; d++) a += qs[p][d] * in_b[Dn + h * 64 + d];
            c0[h * 8 + p] = a * 0.125f;
        }
        return;
    }
    // ---- prep: per-batch scan, recent gather indices, summary mask
    int b = blockIdx.x - 64, t = threadIdx.x;
    int f = *flag;
    const int SP = Sn - 1;                    // 2047
    if (t < RECn) rsrc[b * RECn + t] = -1;
    int base = t * 8;
    unsigned char m[8];
    int cnt = 0;
#pragma unroll
    for (int i = 0; i < 8; i++) {
        int idx = base + i;
        m[i] = (idx < SP) ? (mask_at(raw, f, (size_t)b * Sn + 1 + idx) ? 1 : 0) : 0;
        cnt += m[i];
    }
    lc[t] = cnt;
    __syncthreads();
    for (int off = 1; off < 256; off <<= 1) {
        int add = (t >= off) ? lc[t - off] : 0;
        __syncthreads();
        lc[t] += add;
        __syncthreads();
    }
    int total = lc[255];
    int run = lc[t] - cnt;                    // exclusive prefix
#pragma unroll
    for (int i = 0; i < 8; i++) {
        if (m[i]) {
            run++;
            int rank = total - run;
            if (rank < RECn) rsrc[b * RECn + (RECn - 1 - rank)] = base + i + 1;
        }
    }
    if (t == 0) totals[b] = total;
    if (t < Tn) {
        float mv;
        if (t == 0) mv = mask_at(raw, f, (size_t)b * Sn) ? 1.0f : 0.0f;
        else if (t < 1 + Pn) mv = 1.0f;
        else mv = ((t - 9) >= RECn - total) ? 1.0f : 0.0f;
        maskf[b * Tn + t] = mv;
    }
}

// ---------------------------------------------------------------- scores[b,hp,s] = hidden[b,s,:]@A[hp,:] + c0 (MFMA bf16), masked
// 1024 blocks x 256 thr (4 waves, 4 blocks/CU). Tile 32 s x 128 hp, BK=32.
// B-stage is a LINEAR 8KB DMA from Atile (1 request/wave-instr); A (hidden)
// staged per-row (8 requests/instr). Double-buffered global_load_lds, one
// barrier per K-step; swizzled LDS reads (2-way, free).
__global__ __launch_bounds__(256) void scores_mfma(const float* __restrict__ hidden,
                                                   const short* __restrict__ Atile,
                                                   const float* __restrict__ c0,
                                                   const void* __restrict__ raw,
                                                   const int* __restrict__ flag,
                                                   float* __restrict__ scores) {
    __shared__ float Af[2][32 * 32];          // A: slot16B = s*8 + (j ^ (s&7))
    __shared__ short Bs[2][128 * 32];         // B: LDS image of Atile chunk
    int tid = threadIdx.x, wave = tid >> 6, lane = tid & 63;
    int l15 = lane & 15, q = lane >> 4;
    int m0 = blockIdx.x * 32;
    int b = m0 >> 11, s_base = m0 & 2047;
    int ws = wave >> 1, wh = wave & 1;
    int s0 = ws * 16, hp0 = wh * 64;

    auto stage = [&](int bb, int k0) {
        {                                     // A: 256 slots of 16B (1/thread)
            int s = tid >> 3, j = (tid & 7) ^ (s & 7);
            gload_lds16(hidden + (size_t)(m0 + s) * Dn + k0 + j * 4, &Af[bb][tid * 4]);
        }
        const short* src = Atile + (size_t)(k0 >> 5) * 4096;
#pragma unroll
        for (int u = 0; u < 2; u++) {         // B: linear 8KB chunk copy
            int i = tid + u * 256;
            gload_lds16(src + i * 8, &Bs[bb][i * 8]);
        }
    };

    f32x4 acc[4] = {};
    stage(0, 0);
    __syncthreads();

    for (int t = 0; t < 32; t++) {
        int bb = t & 1;
        if (t + 1 < 32) stage(bb ^ 1, (t + 1) * 32);
        short8 av;
        {
            int s = s0 + l15;
            int base = s * 8;
            f32x4 lo = *(const f32x4*)&Af[bb][(base + ((2 * q) ^ (s & 7))) * 4];
            f32x4 hi = *(const f32x4*)&Af[bb][(base + ((2 * q + 1) ^ (s & 7))) * 4];
#pragma unroll
            for (int i = 0; i < 4; i++) { av[i] = f2bf(lo[i]); av[i + 4] = f2bf(hi[i]); }
        }
#pragma unroll
        for (int f = 0; f < 4; f++) {
            int hp = hp0 + f * 16 + l15;
            short8 bv = *(const short8*)&Bs[bb][(hp * 4 + (q ^ ((hp >> 1) & 3))) * 8];
            acc[f] = __builtin_amdgcn_mfma_f32_16x16x32_bf16(av, bv, acc[f], 0, 0, 0);
        }
        __syncthreads();                      // one barrier per K-step
    }

    int fl = *flag;
    int srow = s_base + s0 + q * 4;
    size_t vbase = (size_t)b * Sn + srow;
    bool ok0 = mask_at(raw, fl, vbase), ok1 = mask_at(raw, fl, vbase + 1);
    bool ok2 = mask_at(raw, fl, vbase + 2), ok3 = mask_at(raw, fl, vbase + 3);
#pragma unroll
    for (int f = 0; f < 4; f++) {
        int hp = hp0 + f * 16 + l15;
        float cc = c0[hp];
        f32x4 st;
        st[0] = ok0 ? acc[f][0] + cc : -1.0e9f;
        st[1] = ok1 ? acc[f][1] + cc : -1.0e9f;
        st[2] = ok2 ? acc[f][2] + cc : -1.0e9f;
        st[3] = ok3 ? acc[f][3] + cc : -1.0e9f;
        *(f32x4*)(scores + (size_t)(b * 128 + hp) * Sn + srow) = st;
    }
}

// ---------------------------------------------------------------- softmax over s; writes bf16 attn
__global__ __launch_bounds__(256) void softmax_kernel(const float* __restrict__ scores,
                                                      short* __restrict__ attn_bf) {
    const float* row = scores + (size_t)blockIdx.x * Sn;
    short* orow = attn_bf + (size_t)blockIdx.x * Sn;
    int t = threadIdx.x;
    __shared__ float red[256];
    f32x4 v0 = *(const f32x4*)(row + t * 8);
    f32x4 v1 = *(const f32x4*)(row + t * 8 + 4);
    float mx = -1.0e30f;
#pragma unroll
    for (int i = 0; i < 4; i++) { mx = fmaxf(mx, v0[i]); mx = fmaxf(mx, v1[i]); }
    red[t] = mx;
    __syncthreads();
    for (int off = 128; off > 0; off >>= 1) {
        if (t < off) red[t] = fmaxf(red[t], red[t + off]);
        __syncthreads();
    }
    mx = red[0];
    __syncthreads();
    float e[8];
    float sum = 0.0f;
#pragma unroll
    for (int i = 0; i < 4; i++) {
        e[i] = expf(v0[i] - mx); sum += e[i];
        e[i + 4] = expf(v1[i] - mx); sum += e[i + 4];
    }
    red[t] = sum;
    __syncthreads();
    for (int off = 128; off > 0; off >>= 1) {
        if (t < off) red[t] += red[t + off];
        __syncthreads();
    }
    float inv = 1.0f / red[0];
    short8 o;
#pragma unroll
    for (int i = 0; i < 8; i++) o[i] = f2bf(e[i] * inv);
    *(short8*)(orow + t * 8) = o;
}

// ---------------------------------------------------------------- U partials (bf16): Up[b,hp,c] = sum_{s in z-chunk} attn*hidden
// grid (16 c-tiles of 64, 16 b, 4 z) x 512 threads. Coalesced transpose
// staging (4x256B/instr), LDS pitch 520; attn streams 4-deep; barrier-free.
__global__ __launch_bounds__(512) void U_mfma(const short* __restrict__ attn_bf,
                                              const float* __restrict__ hidden,
                                              short* __restrict__ Up0,
                                              short* __restrict__ Up1,
                                              short* __restrict__ Up2,
                                              short* __restrict__ Up3) {
    __shared__ short Hs[64 * UPITCH];         // 64 c x 512 s (pitch 520), swizzled
    int n0 = blockIdx.x * 64, b = blockIdx.y, z = blockIdx.z;
    int zbase = z * 512;
    short* Up = (z == 0) ? Up0 : (z == 1) ? Up1 : (z == 2) ? Up2 : Up3;
    int tid = threadIdx.x, wave = tid >> 6, lane = tid & 63;
    int l15 = lane & 15, q = lane >> 4;

    {   // coalesced transpose staging
        int slot = tid & 15, rgrp = tid >> 4;
        const float* srcb = hidden + ((size_t)b * Sn + zbase) * Dn + n0 + slot * 4;
#pragma unroll
        for (int p = 0; p < 16; p++) {
            int row = p * 32 + rgrp;
            f32x4 v = *(const f32x4*)(srcb + (size_t)row * Dn);
#pragma unroll
            for (int i = 0; i < 4; i++) {
                int c = slot * 4 + i;
                Hs[c * UPITCH + (row ^ ((c & 7) << 3))] = f2bf(v[i]);
            }
        }
    }
    __syncthreads();                          // the only barrier

    const short* ap = attn_bf + ((size_t)b * 128 + wave * 16 + l15) * Sn + zbase + q * 8;
    f32x4 acc[4] = {};
    short8 pa4[4];
#pragma unroll
    for (int d = 0; d < 4; d++) pa4[d] = *(const short8*)(ap + d * 32);
#pragma unroll
    for (int ic = 0; ic < 16; ic++) {
        short8 av = pa4[ic & 3];
        if (ic + 4 < 16) pa4[ic & 3] = *(const short8*)(ap + (ic + 4) * 32);
#pragma unroll
        for (int nf = 0; nf < 4; nf++) {
            int c = nf * 16 + l15;
            int ks = (ic * 32 + q * 8) ^ ((c & 7) << 3);
            short8 bv = *(const short8*)(&Hs[c * UPITCH + ks]);
            acc[nf] = __builtin_amdgcn_mfma_f32_16x16x32_bf16(av, bv, acc[nf], 0, 0, 0);
        }
    }
    int hp = wave * 16 + q * 4;
#pragma unroll
    for (int nf = 0; nf < 4; nf++) {
        int c = n0 + nf * 16 + l15;
        short* up = Up + (size_t)(b * 128 + hp) * Dn + c;
#pragma unroll
        for (int r = 0; r < 4; r++) up[(size_t)r * Dn] = f2bf(acc[nf][r]);
    }
}

// ---------------------------------------------------------------- ctx[bp, h*64+d] = (sum Up)[b,h*8+p,:] . Wv[h*64+d,:] + bv  (MFMA)
__global__ __launch_bounds__(64) void ctx_mfma(const short* __restrict__ Up0,
                                               const short* __restrict__ Up1,
                                               const short* __restrict__ Up2,
                                               const short* __restrict__ Up3,
                                               const float* __restrict__ in_w,
                                               const float* __restrict__ in_b,
                                               float* __restrict__ ctx) {
    int bh = blockIdx.x, b = bh >> 4, h = bh & 15;
    int lane = threadIdx.x & 63, l15 = lane & 15, koff = (lane >> 4) * 8;
    int p = l15 & 7;
    size_t uoff = ((size_t)b * 128 + h * 8 + p) * Dn + koff;
    const float* wv = in_w + (size_t)(2 * Dn + h * 64 + l15) * Dn + koff;
    f32x4 acc[4] = {};
    for (int k0 = 0; k0 < Dn; k0 += 32) {
        short8 s0 = *(const short8*)(Up0 + uoff + k0);
        short8 s1 = *(const short8*)(Up1 + uoff + k0);
        short8 s2 = *(const short8*)(Up2 + uoff + k0);
        short8 s3 = *(const short8*)(Up3 + uoff + k0);
        short8 av;
#pragma unroll
        for (int i = 0; i < 8; i++)
            av[i] = f2bf((bf2f(s0[i]) + bf2f(s1[i])) + (bf2f(s2[i]) + bf2f(s3[i])));
#pragma unroll
        for (int nt = 0; nt < 4; nt++) {
            f32x4 w0 = *(const f32x4*)(wv + (size_t)nt * 16 * Dn + k0);
            f32x4 w1 = *(const f32x4*)(wv + (size_t)nt * 16 * Dn + k0 + 4);
            short8 bv;
#pragma unroll
            for (int i = 0; i < 4; i++) { bv[i] = f2bf(w0[i]); bv[i + 4] = f2bf(w1[i]); }
            acc[nt] = __builtin_amdgcn_mfma_f32_16x16x32_bf16(av, bv, acc[nt], 0, 0, 0);
        }
    }
    if (lane < 32) {                          // rows 0-7 valid (p)
        int prow = (lane >> 4) * 4;
#pragma unroll
        for (int nt = 0; nt < 4; nt++) {
            int d = h * 64 + nt * 16 + l15;
            float bias = in_b[2 * Dn + d];
#pragma unroll
            for (int r = 0; r < 4; r++)
                ctx[(size_t)(b * 8 + prow + r) * Dn + d] = acc[nt][r] + bias;
        }
    }
}

// ---------------------------------------------------------------- pooled = ctx @ out_w^T + out_b (MFMA, f32 operands cvt in-reg)
__global__ __launch_bounds__(256) void pooled_mfma(const float* __restrict__ A,
                                                   const float* __restrict__ B,
                                                   const float* __restrict__ bias,
                                                   float* __restrict__ C, int M) {
    int wave = threadIdx.x >> 6, lane = threadIdx.x & 63;
    int l15 = lane & 15, koff = (lane >> 4) * 8;
    int m0 = blockIdx.x * 64 + (wave >> 1) * 32;
    int n0 = blockIdx.y * 64 + (wave & 1) * 32;
    f32x4 acc[2][2] = {};
    int ra0 = min(m0 + l15, M - 1);
    int ra1 = min(m0 + 16 + l15, M - 1);
    const float* a0p = A + (size_t)ra0 * Dn + koff;
    const float* a1p = A + (size_t)ra1 * Dn + koff;
    const float* b0p = B + (size_t)(n0 + l15) * Dn + koff;
    const float* b1p = B + (size_t)(n0 + 16 + l15) * Dn + koff;
    for (int k0 = 0; k0 < Dn; k0 += 32) {
        short8 av0, av1, bv0, bv1;
        f32x4 x, y;
        x = *(const f32x4*)(a0p + k0); y = *(const f32x4*)(a0p + k0 + 4);
#pragma unroll
        for (int i = 0; i < 4; i++) { av0[i] = f2bf(x[i]); av0[i + 4] = f2bf(y[i]); }
        x = *(const f32x4*)(a1p + k0); y = *(const f32x4*)(a1p + k0 + 4);
#pragma unroll
        for (int i = 0; i < 4; i++) { av1[i] = f2bf(x[i]); av1[i + 4] = f2bf(y[i]); }
        x = *(const f32x4*)(b0p + k0); y = *(const f32x4*)(b0p + k0 + 4);
#pragma unroll
        for (int i = 0; i < 4; i++) { bv0[i] = f2bf(x[i]); bv0[i + 4] = f2bf(y[i]); }
        x = *(const f32x4*)(b1p + k0); y = *(const f32x4*)(b1p + k0 + 4);
#pragma unroll
        for (int i = 0; i < 4; i++) { bv1[i] = f2bf(x[i]); bv1[i + 4] = f2bf(y[i]); }
        acc[0][0] = __builtin_amdgcn_mfma_f32_16x16x32_bf16(av0, bv0, acc[0][0], 0, 0, 0);
        acc[0][1] = __builtin_amdgcn_mfma_f32_16x16x32_bf16(av0, bv1, acc[0][1], 0, 0, 0);
        acc[1][0] = __builtin_amdgcn_mfma_f32_16x16x32_bf16(av1, bv0, acc[1][0], 0, 0, 0);
        acc[1][1] = __builtin_amdgcn_mfma_f32_16x16x32_bf16(av1, bv1, acc[1][1], 0, 0, 0);
    }
#pragma unroll
    for (int mf = 0; mf < 2; mf++) {
        int row0 = m0 + mf * 16 + (lane >> 4) * 4;
#pragma unroll
        for (int nf = 0; nf < 2; nf++) {
            int col = n0 + nf * 16 + l15;
            float bval = bias[col];
#pragma unroll
            for (int r = 0; r < 4; r++) {
                int row = row0 + r;
                if (row < M) C[(size_t)row * Dn + col] = acc[mf][nf][r] + bval;
            }
        }
    }
}

// ---------------------------------------------------------------- merged W-GEMMs: z=0: c1=lnv@Wv^T+bv, z=1: c2=lng@Wg^T+bg
__global__ __launch_bounds__(256) void wgemm_mfma(const short* __restrict__ lnv,
                                                  const short* __restrict__ lng,
                                                  const float* __restrict__ Wv,
                                                  const float* __restrict__ Wg,
                                                  const float* __restrict__ bv_,
                                                  const float* __restrict__ bg_,
                                                  float* __restrict__ c1,
                                                  float* __restrict__ c2, int M) {
    int z = blockIdx.z;
    const short* Abf = z ? lng : lnv;
    const float* Bw = z ? Wg : Wv;
    const float* bias = z ? bg_ : bv_;
    float* C = z ? c2 : c1;
    int wave = threadIdx.x >> 6, lane = threadIdx.x & 63;
    int l15 = lane & 15, koff = (lane >> 4) * 8;
    int m0 = blockIdx.x * 64 + (wave >> 1) * 32;
    int n0 = blockIdx.y * 64 + (wave & 1) * 32;
    f32x4 acc[2][2] = {};
    int ra0 = min(m0 + l15, M - 1);
    int ra1 = min(m0 + 16 + l15, M - 1);
    const short* a0p = Abf + (size_t)ra0 * Dn + koff;
    const short* a1p = Abf + (size_t)ra1 * Dn + koff;
    const float* b0p = Bw + (size_t)(n0 + l15) * Dn + koff;
    const float* b1p = Bw + (size_t)(n0 + 16 + l15) * Dn + koff;
    for (int k0 = 0; k0 < Dn; k0 += 32) {
        short8 av0 = *(const short8*)(a0p + k0);
        short8 av1 = *(const short8*)(a1p + k0);
        short8 bv0, bv1;
        f32x4 x, y;
        x = *(const f32x4*)(b0p + k0); y = *(const f32x4*)(b0p + k0 + 4);
#pragma unroll
        for (int i = 0; i < 4; i++) { bv0[i] = f2bf(x[i]); bv0[i + 4] = f2bf(y[i]); }
        x = *(const f32x4*)(b1p + k0); y = *(const f32x4*)(b1p + k0 + 4);
#pragma unroll
        for (int i = 0; i < 4; i++) { bv1[i] = f2bf(x[i]); bv1[i + 4] = f2bf(y[i]); }
        acc[0][0] = __builtin_amdgcn_mfma_f32_16x16x32_bf16(av0, bv0, acc[0][0], 0, 0, 0);
        acc[0][1] = __builtin_amdgcn_mfma_f32_16x16x32_bf16(av0, bv1, acc[0][1], 0, 0, 0);
        acc[1][0] = __builtin_amdgcn_mfma_f32_16x16x32_bf16(av1, bv0, acc[1][0], 0, 0, 0);
        acc[1][1] = __builtin_amdgcn_mfma_f32_16x16x32_bf16(av1, bv1, acc[1][1], 0, 0, 0);
    }
#pragma unroll
    for (int mf = 0; mf < 2; mf++) {
        int row0 = m0 + mf * 16 + (lane >> 4) * 4;
#pragma unroll
        for (int nf = 0; nf < 2; nf++) {
            int col = n0 + nf * 16 + l15;
            float bval = bias[col];
#pragma unroll
            for (int r = 0; r < 4; r++) {
                int row = row0 + r;
                if (row < M) C[(size_t)row * Dn + col] = acc[mf][nf][r] + bval;
            }
        }
    }
}

// ---------------------------------------------------------------- block sum helper
__device__ __forceinline__ float block_sum(float v, float* red) {
    int tid = threadIdx.x;
    red[tid] = v;
    __syncthreads();
    for (int off = 128; off > 0; off >>= 1) {
        if (tid < off) red[tid] += red[tid + off];
        __syncthreads();
    }
    float r = red[0];
    __syncthreads();
    return r;
}

// ---------------------------------------------------------------- build summary row + LN_pma + LN_v / LN_g (bf16 out)
__global__ void summary_ln_kernel(const float* __restrict__ hidden,
                                  const float* __restrict__ queries,
                                  const float* __restrict__ pooled,
                                  const int* __restrict__ rsrc,
                                  const float* __restrict__ gpma, const float* __restrict__ bpma,
                                  const float* __restrict__ gv, const float* __restrict__ bv,
                                  const float* __restrict__ gg, const float* __restrict__ bg,
                                  short* __restrict__ lnv, short* __restrict__ lng) {
    __shared__ float red[256];
    int b = blockIdx.x, t = blockIdx.y, tid = threadIdx.x;
    float x[4];
    if (t == 0) {
#pragma unroll
        for (int i = 0; i < 4; i++)
            x[i] = hidden[(size_t)b * Sn * Dn + tid + i * 256];
    } else if (t < 1 + Pn) {
        int p = t - 1;
#pragma unroll
        for (int i = 0; i < 4; i++) {
            int c = tid + i * 256;
            x[i] = queries[p * Dn + c] + pooled[((size_t)b * Pn + p) * Dn + c];
        }
    } else {
        int src = rsrc[b * RECn + (t - 9)];
        if (src >= 0) {
#pragma unroll
            for (int i = 0; i < 4; i++)
                x[i] = hidden[((size_t)b * Sn + src) * Dn + tid + i * 256];
        } else {
#pragma unroll
            for (int i = 0; i < 4; i++) x[i] = 0.0f;
        }
    }
    if (t >= 1 && t < 1 + Pn) {
        float mu = block_sum(x[0] + x[1] + x[2] + x[3], red) * (1.0f / Dn);
        float d2 = 0.0f;
#pragma unroll
        for (int i = 0; i < 4; i++) { float d = x[i] - mu; d2 += d * d; }
        float inv = rsqrtf(block_sum(d2, red) * (1.0f / Dn) + 1e-5f);
#pragma unroll
        for (int i = 0; i < 4; i++) {
            int c = tid + i * 256;
            x[i] = (x[i] - mu) * inv * gpma[c] + bpma[c];
        }
    }
    float mu = block_sum(x[0] + x[1] + x[2] + x[3], red) * (1.0f / Dn);
    float d2 = 0.0f;
#pragma unroll
    for (int i = 0; i < 4; i++) { float d = x[i] - mu; d2 += d * d; }
    float inv = rsqrtf(block_sum(d2, red) * (1.0f / Dn) + 1e-5f);
    size_t row = (size_t)(b * Tn + t) * Dn;
#pragma unroll
    for (int i = 0; i < 4; i++) {
        int c = tid + i * 256;
        float xh = (x[i] - mu) * inv;
        lnv[row + c] = f2bf(xh * gv[c] + bv[c]);
        lng[row + c] = f2bf(xh * gg[c] + bg[c]);
    }
}

// ---------------------------------------------------------------- gated = sigmoid(c2) * silu(c1) * mask
__global__ void gated_kernel(const float* __restrict__ c1, const float* __restrict__ c2,
                             const float* __restrict__ maskf, float* __restrict__ out) {
    int gi = blockIdx.x * blockDim.x + threadIdx.x;
    int row = gi >> 10;
    float m = maskf[row];
    float a = c1[gi], g = c2[gi];
    float sv = a / (1.0f + expf(-a));
    float sg = 1.0f / (1.0f + expf(-g));
    out[gi] = sg * sv * m;
}

// ================================================================ launch
extern "C" void kernel_launch(void* const* d_in, const int* in_sizes, int n_in,
                              void* d_out, int out_size, void* d_ws, size_t ws_size,
                              hipStream_t stream) {
    const float* hidden = (const float*)d_in[0];
    const void* valid_raw = d_in[1];
    const float* queries = (const float*)d_in[2];
    const float* in_w = (const float*)d_in[3];
    const float* in_b = (const float*)d_in[4];
    const float* out_w = (const float*)d_in[5];
    const float* out_b = (const float*)d_in[6];
    const float* ln_pma_g = (const float*)d_in[7];
    const float* ln_pma_b = (const float*)d_in[8];
    const float* ln_v_g = (const float*)d_in[9];
    const float* ln_v_b = (const float*)d_in[10];
    const float* W_v = (const float*)d_in[11];
    const float* b_v = (const float*)d_in[12];
    const float* ln_g_g = (const float*)d_in[13];
    const float* ln_g_b = (const float*)d_in[14];
    const float* W_g = (const float*)d_in[15];
    const float* b_g = (const float*)d_in[16];

    float* ws = (float*)d_ws;
    float* out = (float*)d_out;

    // workspace layout (float offsets):
    float* SC      = ws;                         // scores f32: 4,194,304 f (dead after softmax)
    short* attn_bf = (short*)(ws + 4194304);     // 4,194,304 shorts = 2,097,152 f
    short* Up0     = (short*)ws;                 // bf16 partials overlay dead SC:
    short* Up1     = (short*)(ws + 1048576);     //   each 2,097,152 shorts = 1,048,576 f
    short* Up2     = (short*)(ws + 2097152);
    short* Up3     = (short*)(ws + 3145728);     // ends 4,194,304 (SC region exactly)
    float* qbuf    = ws + 10485760;              // 8,192
    short* Atile   = (short*)(ws + 10493952);    // 131,072 shorts = 65,536 f
    float* c0      = ws + 10559488;              // 256
    float* ctx     = ws + 10559744;              // 131,072
    float* pooled  = ws + 10690816;              // 131,072
    int*   ivals   = (int*)(ws + 11870464);
    int* totals = ivals;                         // 16
    int* rsrc = ivals + 16;                      // 1024
    int* flag = ivals + 16 + 1024;               // 16
    // post-ctx overlays (Up0..3 dead after ctx):
    short* lnv_bf = (short*)ws;                  // 1168*1024 shorts
    short* lng_bf = (short*)(ws + 622592);
    float* c1 = ws + 1245184;
    float* c2 = ws + 2441216;                    // ends 3,637,248 OK
    float* maskf = out + (size_t)Bn * Tn * Dn;

    const int M2 = Bn * Tn; // 1168

    setup1_kernel<<<2049, 256, 0, stream>>>(queries, in_w, in_b,
                                            (const unsigned char*)valid_raw, qbuf, flag);
    setup2_kernel<<<80, 256, 0, stream>>>(qbuf, in_w, in_b, valid_raw, flag,
                                          Atile, c0, totals, rsrc, maskf);
    scores_mfma<<<(Bn * Sn) / 32, 256, 0, stream>>>(hidden, Atile, c0, valid_raw, flag, SC);
    softmax_kernel<<<Bn * 128, 256, 0, stream>>>(SC, attn_bf);
    U_mfma<<<dim3(16, Bn, 4), 512, 0, stream>>>(attn_bf, hidden, Up0, Up1, Up2, Up3);
    ctx_mfma<<<Bn * Hn, 64, 0, stream>>>(Up0, Up1, Up2, Up3, in_w, in_b, ctx);
    pooled_mfma<<<dim3(2, 16), 256, 0, stream>>>(ctx, out_w, out_b, pooled, Bn * Pn);
    summary_ln_kernel<<<dim3(Bn, Tn), 256, 0, stream>>>(hidden, queries, pooled, rsrc,
                                                        ln_pma_g, ln_pma_b, ln_v_g, ln_v_b,
                                                        ln_g_g, ln_g_b, lnv_bf, lng_bf);
    wgemm_mfma<<<dim3((M2 + 63) / 64, 16, 2), 256, 0, stream>>>(lnv_bf, lng_bf, W_v, W_g,
                                                                b_v, b_g, c1, c2, M2);
    gated_kernel<<<(Bn * Tn * Dn) / 256, 256, 0, stream>>>(c1, c2, maskf, out);
}